// Round 6
// baseline (326.343 us; speedup 1.0000x reference)
//
#include <hip/hip_runtime.h>
#include <hip/hip_bf16.h>

#define BB 2
#define NN 2048
#define DD 128
#define HH 8
#define HD 1024
#define OUTD 256
// (1/sqrt(2048)) * log2(e): p = exp2(s * a') == exp(s * a / sqrt(2048))
#define ASCALE 0.031879357f

typedef __bf16 bf16x8 __attribute__((ext_vector_type(8)));
typedef float f32x4 __attribute__((ext_vector_type(4)));
typedef _Float16 f16x8 __attribute__((ext_vector_type(8)));

__device__ __forceinline__ unsigned short f2bf(float f) {
    union { float f; unsigned int u; } v; v.f = f;
    unsigned int r = (v.u + 0x7FFFu + ((v.u >> 16) & 1u)) >> 16;
    return (unsigned short)r;
}
__device__ __forceinline__ float bf2f(unsigned short s) {
    union { unsigned int u; float f; } v; v.u = ((unsigned int)s) << 16;
    return v.f;
}
__device__ __forceinline__ unsigned short f2h_bits(float f) {
    _Float16 h = (_Float16)f;
    union { _Float16 h; unsigned short u; } v; v.h = h;
    return v.u;
}
// async global->LDS, 16 B per lane; lds dst = wave-uniform base + lane*16
__device__ __forceinline__ void gl_lds16(const void* g, void* l) {
    __builtin_amdgcn_global_load_lds(
        (const __attribute__((address_space(1))) unsigned int*)g,
        (__attribute__((address_space(3))) unsigned int*)l,
        16, 0, 0);
}

// ---------------- prep: adjsumT + Xb cast + weight transposes ----------------
// grid 4648: [0,4096) adjsumT, [4096,4608) Xb, [4608,4632) WT, [4632,4648) WoutT(f16)
__global__ __launch_bounds__(256) void prep_kernel(
    const float* __restrict__ X,
    const float4* __restrict__ adj,      // [B][N][N] of float4 (W=4)
    const float* __restrict__ Wq,
    const float* __restrict__ Wk,
    const float* __restrict__ Wv,
    const float* __restrict__ Wout,
    unsigned short* __restrict__ Xb,     // [B][N][D] bf16
    unsigned short* __restrict__ WT,     // [3][H][e][d] bf16
    unsigned short* __restrict__ WoutT,  // [OUT][H*D] f16
    unsigned short* __restrict__ AsumT)  // [B][key][q] bf16, pre-scaled by ASCALE
{
    __shared__ unsigned short T[128 * 136];   // reused by all transpose branches
    const int bid = blockIdx.x;
    const int t = threadIdx.x;

    if (bid < 4096) {                         // adjsumT: 64q x 32key tile, transposed out
        const int b = bid >> 11, rem = bid & 2047;
        const int q0 = (rem >> 6) * 64, k0 = (rem & 63) * 32;
        const int q_l = t >> 2, kg = t & 3;
        const float4* arow = adj + ((size_t)(b * NN + q0 + q_l)) * NN + k0 + kg * 8;
        #pragma unroll
        for (int j = 0; j < 8; ++j) {
            float4 v = arow[j];
            T[(kg * 8 + j) * 68 + q_l] = f2bf(((v.x + v.y) + (v.z + v.w)) * ASCALE);
        }
        __syncthreads();
        const int key = t >> 3, ch = t & 7;
        *(uint4*)&AsumT[(size_t)(b * NN + k0 + key) * NN + q0 + ch * 8] =
            *(const uint4*)&T[key * 68 + ch * 8];
    } else if (bid < 4608) {                  // Xb cast, vectorized
        int i4 = ((bid - 4096) * 256 + t) * 4;
        float4 v = *(const float4*)(X + i4);
        unsigned short u[4] = {f2bf(v.x), f2bf(v.y), f2bf(v.z), f2bf(v.w)};
        *(ushort4*)(Xb + i4) = *(const ushort4*)u;
    } else if (bid < 4632) {                  // WT: [h][d][e] -> [mat][h][e][d] bf16
        const int mh = bid - 4608;
        const int mat = mh >> 3, h = mh & 7;
        const float* Wm = (mat == 0) ? Wq : ((mat == 1) ? Wk : Wv);
        Wm += (size_t)h * DD * DD;
        #pragma unroll
        for (int i = 0; i < 16; ++i) {
            int lin = i * 256 + t;
            int d = lin >> 5, e = (lin & 31) * 4;
            float4 v = *(const float4*)(Wm + (size_t)d * DD + e);
            unsigned short u[4] = {f2bf(v.x), f2bf(v.y), f2bf(v.z), f2bf(v.w)};
            *(uint2*)&T[d * 136 + e] = *(const uint2*)u;
        }
        __syncthreads();
        const int e = t >> 1, nh = t & 1;
        unsigned short* Wo = WT + ((size_t)mat * HH + h) * (DD * DD) + (size_t)e * DD + nh * 64;
        #pragma unroll
        for (int j = 0; j < 8; ++j) {
            unsigned short tmp[8];
            #pragma unroll
            for (int k = 0; k < 8; ++k)
                tmp[k] = T[(nh * 64 + j * 8 + k) * 136 + e];
            *(uint4*)(Wo + j * 8) = *(const uint4*)tmp;
        }
    } else {                                  // WoutT: [k][o] -> [o][k] f16
        const int kb = bid - 4632;
        #pragma unroll
        for (int i = 0; i < 16; ++i) {
            int lin = i * 256 + t;
            int k = lin >> 6, o = (lin & 63) * 4;
            float4 v = *(const float4*)(Wout + (size_t)(kb * 64 + k) * OUTD + o);
            unsigned short u[4] = {f2h_bits(v.x), f2h_bits(v.y), f2h_bits(v.z), f2h_bits(v.w)};
            *(uint2*)&T[k * 264 + o] = *(const uint2*)u;
        }
        __syncthreads();
        unsigned short* Wo = WoutT + (size_t)t * HD + kb * 64;
        #pragma unroll
        for (int j = 0; j < 8; ++j) {
            unsigned short tmp[8];
            #pragma unroll
            for (int k = 0; k < 8; ++k)
                tmp[k] = T[(j * 8 + k) * 264 + t];
            *(uint4*)(Wo + j * 8) = *(const uint4*)tmp;
        }
    }
}

// ---------------- projections q/k/v ----------------
// grid (N/64, B*H, 3); block 256. mat: 0=Q(bf16), 1=K(bf16), 2=V(f16, transposed)
__global__ __launch_bounds__(256) void proj_kernel(
    const unsigned short* __restrict__ Xb,
    const unsigned short* __restrict__ WT,
    const float* __restrict__ bq, const float* __restrict__ bk, const float* __restrict__ bv,
    unsigned short* __restrict__ Qo, unsigned short* __restrict__ Ko,
    unsigned short* __restrict__ Vt)
{
    const int mat = blockIdx.z;
    const int bh  = blockIdx.y;
    const int b = bh >> 3, h = bh & 7;
    const int n0 = blockIdx.x * 64;
    const int tid = threadIdx.x;
    const int lane = tid & 63, wv = tid >> 6;
    const int m = lane & 15, quad = lane >> 4;

    __shared__ unsigned short Wlds[128 * 136];

    const unsigned short* Wg = WT + ((size_t)mat * HH + h) * (DD * DD);
    #pragma unroll
    for (int i = tid; i < 128 * 16; i += 256) {
        int r = i >> 4, c = i & 15;
        *(uint4*)&Wlds[r * 136 + c * 8] = *(const uint4*)(Wg + r * 128 + c * 8);
    }

    const int row = n0 + wv * 16 + m;
    const unsigned short* Xr = Xb + ((size_t)b * NN + row) * DD;
    bf16x8 af[4];
    #pragma unroll
    for (int kc = 0; kc < 4; ++kc)
        af[kc] = *(const bf16x8*)(Xr + kc * 32 + quad * 8);

    __syncthreads();

    f32x4 acc[8];
    #pragma unroll
    for (int et = 0; et < 8; ++et) acc[et] = (f32x4){0.f, 0.f, 0.f, 0.f};

    #pragma unroll
    for (int kc = 0; kc < 4; ++kc) {
        #pragma unroll
        for (int et = 0; et < 8; ++et) {
            bf16x8 bfrg = *(const bf16x8*)&Wlds[(et * 16 + m) * 136 + kc * 32 + quad * 8];
            acc[et] = __builtin_amdgcn_mfma_f32_16x16x32_bf16(af[kc], bfrg, acc[et], 0, 0, 0);
        }
    }

    const float* bias = (mat == 0) ? bq : ((mat == 1) ? bk : bv);
    if (mat != 2) {
        #pragma unroll
        for (int et = 0; et < 8; ++et) {
            int e = et * 16 + m;
            float bb = bias[h * DD + e];
            #pragma unroll
            for (int reg = 0; reg < 4; ++reg) {
                int r = n0 + wv * 16 + quad * 4 + reg;
                unsigned short v16 = f2bf(acc[et][reg] + bb);
                if (mat == 0) Qo[((size_t)bh * NN + r) * DD + e] = v16;
                else          Ko[((size_t)bh * NN + r) * DD + e] = v16;
            }
        }
    } else {
        // V (fp16): transpose through LDS -> coalesced uint4 stores to Vt[bh][e][n]
        __syncthreads();
        #pragma unroll
        for (int et = 0; et < 8; ++et) {
            int e = et * 16 + m;
            float bb = bias[h * DD + e];
            #pragma unroll
            for (int reg = 0; reg < 4; ++reg)
                Wlds[(wv * 16 + quad * 4 + reg) * 136 + e] = f2h_bits(acc[et][reg] + bb);
        }
        __syncthreads();
        const int e = tid >> 1, nh = tid & 1;
        #pragma unroll
        for (int j = 0; j < 4; ++j) {
            unsigned short tmp[8];
            #pragma unroll
            for (int kk = 0; kk < 8; ++kk)
                tmp[kk] = Wlds[(nh * 32 + j * 8 + kk) * 136 + e];
            *(uint4*)(Vt + ((size_t)bh * DD + e) * NN + n0 + nh * 32 + j * 8) = *(uint4*)tmp;
        }
    }
}

// ---------------- flash attention, split-K x3, adj via LDS, fp16 PV ----------------
// grid 768 (3 blocks/CU). L -> ks(3) x [qt(16), h(8), b(2)]. q-tile 128, TK=32.
// K/V double-buffered (gl_lds16, XOR swizzle); adj tile single-buffered (extra cheap
// barrier after its reads, before restage). P,V fp16; Q,K bf16.
__global__ __launch_bounds__(256, 3) void attn_kernel(
    const unsigned short* __restrict__ Q,
    const unsigned short* __restrict__ K,
    const unsigned short* __restrict__ Vt,      // f16 bits
    const unsigned short* __restrict__ AsumT,   // bf16 [B][key][q], pre-scaled
    _Float16* __restrict__ Opart,               // [3][B*N][HD] fp16 partials (concat layout)
    float* __restrict__ Lpart)                  // [3][B*N][H] fp32 partial row-sums
{
    const int L = blockIdx.x;
    const int ks = L % 3;
    const int t1 = L / 3;
    const int qt = t1 & 15, h = (t1 >> 4) & 7, b = t1 >> 7;
    const int bh = b * HH + h;
    const int q0 = qt * 128;
    const int kstart = (ks == 0) ? 0 : (704 + (ks - 1) * 672);
    const int nkt = (ks == 0) ? 22 : 21;
    const int tid = threadIdx.x;
    const int lane = tid & 63, wv = tid >> 6;
    const int m = lane & 15, quad = lane >> 4;

    __shared__ unsigned short Kb[2][32 * 128];   // bf16 [key][d] swizzled, 8 KB each
    __shared__ unsigned short Vb[2][128 * 32];   // f16 [d][key] swizzled, 8 KB each
    __shared__ unsigned short Ab[32 * 128];      // bf16 [key][q] swizzled, 8 KB
    __shared__ _Float16 Plds[4][2][16 * 40];     // per-wave, per-q-group P, 10 KB
    // total 51.2 KB -> 3 blocks/CU

    const unsigned short* Kbase = K + (size_t)bh * NN * DD;
    const unsigned short* Vbase = Vt + (size_t)bh * DD * NN;
    const unsigned short* ATb   = AsumT + (size_t)b * NN * NN;

    // Q fragments: 2 q-groups of 16 rows, register-resident
    bf16x8 qf[2][4];
    #pragma unroll
    for (int qg = 0; qg < 2; ++qg) {
        const unsigned short* Qr = Q + ((size_t)bh * NN + q0 + wv * 32 + qg * 16 + m) * DD;
        #pragma unroll
        for (int kc = 0; kc < 4; ++kc)
            qf[qg][kc] = *(const bf16x8*)(Qr + kc * 32 + quad * 8);
    }

    f32x4 o[2][8];
    #pragma unroll
    for (int qg = 0; qg < 2; ++qg)
        #pragma unroll
        for (int dt = 0; dt < 8; ++dt) o[qg][dt] = (f32x4){0.f, 0.f, 0.f, 0.f};
    float li[2][4] = {{0.f,0.f,0.f,0.f},{0.f,0.f,0.f,0.f}};

    // staging lane decomposition
    const int kr4 = lane >> 4, kc16 = lane & 15;  // K: 4 rows x 16 chunks / instr
    const int vr16 = lane >> 2, vc4 = lane & 3;   // V: 16 rows x 4 chunks / instr
    const int akey4 = lane >> 4, aqc = lane & 15; // A: 4 keys x 16 chunks / instr

    #define STAGE_KV(buf, kbase_)                                                          \
        {                                                                                   \
            _Pragma("unroll")                                                               \
            for (int j2 = 0; j2 < 2; ++j2) {                                                \
                const int j = wv * 2 + j2;                                                  \
                const int krow = j * 4 + kr4;                                               \
                gl_lds16(Kbase + (size_t)((kbase_) + krow) * DD + ((kc16 ^ (krow & 15)) * 8),\
                         &Kb[buf][j * 512]);                                                \
                const int vrow = j * 16 + vr16;                                             \
                gl_lds16(Vbase + (size_t)vrow * NN + (kbase_) + ((vc4 ^ ((vr16 >> 1) & 3)) * 8),\
                         &Vb[buf][j * 512]);                                                \
            }                                                                               \
        }
    #define STAGE_A(kbase_)                                                                 \
        {                                                                                   \
            _Pragma("unroll")                                                               \
            for (int j2 = 0; j2 < 2; ++j2) {                                                \
                const int key = wv * 8 + j2 * 4 + akey4;                                    \
                gl_lds16(ATb + (size_t)((kbase_) + key) * NN + q0 + ((aqc ^ (key & 15)) * 8),\
                         &Ab[(wv * 8 + j2 * 4) * 128]);                                     \
            }                                                                               \
        }

    STAGE_KV(0, kstart);
    STAGE_A(kstart);
    __syncthreads();   // vmcnt drain -> tile 0 ready

    for (int kt = 0; kt < nkt; ++kt) {
        const int cb = kt & 1, nb = cb ^ 1;
        const int k0 = kstart + kt * 32;

        // adj from LDS: 4x ds_read_b64 (pre-scaled bf16)
        float areg[2][2][4];
        #pragma unroll
        for (int qg = 0; qg < 2; ++qg) {
            const int qlc = wv * 4 + qg * 2 + (quad >> 1);
            #pragma unroll
            for (int nt = 0; nt < 2; ++nt) {
                ushort4 av = *(const ushort4*)&Ab[(nt * 16 + m) * 128 +
                                                  ((qlc ^ m) * 8) + (quad & 1) * 4];
                areg[qg][nt][0] = bf2f(av.x);
                areg[qg][nt][1] = bf2f(av.y);
                areg[qg][nt][2] = bf2f(av.z);
                areg[qg][nt][3] = bf2f(av.w);
            }
        }
        __syncthreads();  // all waves done reading Ab (LDS-only, cheap barrier)

        // async-stage next tile (K/V into nb, adj into the single Ab)
        if (kt + 1 < nkt) { STAGE_KV(nb, k0 + 32); STAGE_A(k0 + 32); }

        // QK^T: each kf fragment feeds both q-groups (16 MFMA, 8 kf reads)
        f32x4 s[2][2];
        s[0][0] = (f32x4){0.f,0.f,0.f,0.f}; s[0][1] = (f32x4){0.f,0.f,0.f,0.f};
        s[1][0] = (f32x4){0.f,0.f,0.f,0.f}; s[1][1] = (f32x4){0.f,0.f,0.f,0.f};
        #pragma unroll
        for (int kc = 0; kc < 4; ++kc) {
            #pragma unroll
            for (int nt = 0; nt < 2; ++nt) {
                bf16x8 kf = *(const bf16x8*)&Kb[cb][(nt * 16 + m) * 128 + (((kc * 4 + quad) ^ m) * 8)];
                s[0][nt] = __builtin_amdgcn_mfma_f32_16x16x32_bf16(qf[0][kc], kf, s[0][nt], 0, 0, 0);
                s[1][nt] = __builtin_amdgcn_mfma_f32_16x16x32_bf16(qf[1][kc], kf, s[1][nt], 0, 0, 0);
            }
        }

        // p = exp2(s * a)  (a pre-scaled by 1/sqrt(2048)*log2e; bounded, no max needed)
        #pragma unroll
        for (int qg = 0; qg < 2; ++qg)
            #pragma unroll
            for (int nt = 0; nt < 2; ++nt)
                #pragma unroll
                for (int reg = 0; reg < 4; ++reg) {
                    float p = exp2f(s[qg][nt][reg] * areg[qg][nt][reg]);
                    li[qg][reg] += p;
                    Plds[wv][qg][(quad * 4 + reg) * 40 + nt * 16 + m] = (_Float16)p;
                }

        // P x V fp16: each vf fragment feeds both q-groups (16 MFMA, 8 vf reads)
        f16x8 pf0 = *(const f16x8*)&Plds[wv][0][m * 40 + quad * 8];
        f16x8 pf1 = *(const f16x8*)&Plds[wv][1][m * 40 + quad * 8];
        #pragma unroll
        for (int dt = 0; dt < 8; ++dt) {
            f16x8 vf = *(const f16x8*)&Vb[cb][(dt * 16 + m) * 32 + ((quad ^ ((m >> 1) & 3)) * 8)];
            o[0][dt] = __builtin_amdgcn_mfma_f32_16x16x32_f16(pf0, vf, o[0][dt], 0, 0, 0);
            o[1][dt] = __builtin_amdgcn_mfma_f32_16x16x32_f16(pf1, vf, o[1][dt], 0, 0, 0);
        }

        __syncthreads();  // readers done with cb; all staging drained
    }
    #undef STAGE_KV
    #undef STAGE_A

    #pragma unroll
    for (int qg = 0; qg < 2; ++qg) {
        #pragma unroll
        for (int reg = 0; reg < 4; ++reg) {
            float t = li[qg][reg];
            t += __shfl_xor(t, 1);
            t += __shfl_xor(t, 2);
            t += __shfl_xor(t, 4);
            t += __shfl_xor(t, 8);
            li[qg][reg] = t;
        }
        const int rbase = q0 + wv * 32 + qg * 16 + quad * 4;
        if (m == 0) {
            #pragma unroll
            for (int reg = 0; reg < 4; ++reg)
                Lpart[(size_t)(ks * BB * NN + b * NN + rbase + reg) * HH + h] = li[qg][reg];
        }
        #pragma unroll
        for (int reg = 0; reg < 4; ++reg) {
            const size_t obase = (size_t)(ks * BB * NN + b * NN + rbase + reg) * HD + h * DD;
            #pragma unroll
            for (int dt = 0; dt < 8; ++dt)
                Opart[obase + dt * 16 + m] = (_Float16)o[qg][dt][reg];
        }
    }
}

// ---------------- fused combine + output projection ----------------
// grid (128, 4) = 512 blocks (2/CU); M-tile 32, N-tile 64.
// A-frag = ((Op0+Op1+Op2) * linv[row][head]) in fp16; W f16; MFMA f16.
__global__ __launch_bounds__(256) void out_kernel(
    const _Float16* __restrict__ Op,        // [3][B*N][HD]
    const float* __restrict__ Lp,           // [3][B*N][H]
    const unsigned short* __restrict__ WoutT,   // f16 [OUT][HD]
    const float* __restrict__ bout,
    float* __restrict__ out)
{
    const int OFFS = BB * NN * HD;    // 4,194,304
    const int LOFF = BB * NN * HH;    // 32,768
    const int m0 = blockIdx.x * 32;
    const int c0 = blockIdx.y * 64;
    const int tid = threadIdx.x;
    const int lane = tid & 63, wv = tid >> 6;
    const int m = lane & 15, quad = lane >> 4;
    const int mg = wv & 1, cg = wv >> 1;

    __shared__ unsigned short Wlds[64 * 136];
    __shared__ float Llds[32 * 8];

    {   // stage 1/l for the 32 rows x 8 heads
        const int rl = tid >> 3, hh = tid & 7;
        const int ri = m0 + rl;
        float l = Lp[(size_t)ri * HH + hh] + Lp[(size_t)(LOFF + ri * HH) + hh] +
                  Lp[(size_t)(2 * LOFF + ri * HH) + hh];
        Llds[rl * 8 + hh] = 1.0f / l;
    }

    f32x4 acc[2];
    acc[0] = (f32x4){0.f,0.f,0.f,0.f};
    acc[1] = (f32x4){0.f,0.f,0.f,0.f};

    const int row_l = mg * 16 + m;
    const size_t ri = (size_t)(m0 + row_l);

    for (int kc = 0; kc < 8; ++kc) {      // k-chunk == head
        #pragma unroll
        for (int i = tid; i < 64 * 16; i += 256) {
            int rr = i >> 4, c = i & 15;
            *(uint4*)&Wlds[rr * 136 + c * 8] =
                *(const uint4*)(WoutT + (size_t)(c0 + rr) * HD + kc * 128 + c * 8);
        }
        __syncthreads();
        _Float16 hl = (_Float16)Llds[row_l * 8 + kc];
        f16x8 hlv;
        #pragma unroll
        for (int i = 0; i < 8; ++i) hlv[i] = hl;
        #pragma unroll
        for (int j = 0; j < 4; ++j) {
            const size_t abase = ri * HD + kc * 128 + j * 32 + quad * 8;
            f16x8 a0 = *(const f16x8*)(Op + abase);
            f16x8 a1 = *(const f16x8*)(Op + OFFS + abase);
            f16x8 a2 = *(const f16x8*)(Op + 2 * (size_t)OFFS + abase);
            f16x8 afr = ((a0 + a1) + a2) * hlv;
            #pragma unroll
            for (int nt = 0; nt < 2; ++nt) {
                f16x8 bfr = *(const f16x8*)&Wlds[(cg * 32 + nt * 16 + m) * 136 + j * 32 + quad * 8];
                acc[nt] = __builtin_amdgcn_mfma_f32_16x16x32_f16(afr, bfr, acc[nt], 0, 0, 0);
            }
        }
        __syncthreads();
    }

    #pragma unroll
    for (int nt = 0; nt < 2; ++nt) {
        int oc = c0 + cg * 32 + nt * 16 + m;
        float bb = bout[oc];
        #pragma unroll
        for (int reg = 0; reg < 4; ++reg) {
            int rr = m0 + mg * 16 + quad * 4 + reg;
            out[(size_t)rr * OUTD + oc] = acc[nt][reg] + bb;
        }
    }
}

extern "C" void kernel_launch(void* const* d_in, const int* in_sizes, int n_in,
                              void* d_out, int out_size, void* d_ws, size_t ws_size,
                              hipStream_t stream)
{
    const float* X    = (const float*)d_in[0];
    const float* adj  = (const float*)d_in[1];
    const float* Wq   = (const float*)d_in[2];
    const float* bq   = (const float*)d_in[3];
    const float* Wk   = (const float*)d_in[4];
    const float* bk   = (const float*)d_in[5];
    const float* Wv   = (const float*)d_in[6];
    const float* bv   = (const float*)d_in[7];
    const float* Wout = (const float*)d_in[8];
    const float* bout = (const float*)d_in[9];
    float* out = (float*)d_out;

    char* ws = (char*)d_ws;
    unsigned short* Xb    = (unsigned short*)(ws);             // 1,048,576 B (dead after proj)
    unsigned short* WT    = (unsigned short*)(ws + 1048576);   //   786,432 B
    unsigned short* WoutT = (unsigned short*)(ws + 1835008);   //   524,288 B (f16)
    unsigned short* Q     = (unsigned short*)(ws + 2359296);   // 8,388,608 B
    unsigned short* Kp    = (unsigned short*)(ws + 10747904);  // 8,388,608 B
    unsigned short* Vt    = (unsigned short*)(ws + 19136512);  // 8,388,608 B (f16)
    unsigned short* AsumT = (unsigned short*)(ws + 27525120);  // 16,777,216 B
    _Float16*       Opart = (_Float16*)(ws + 44302336);        // 25,165,824 B (ends 69,468,160)
    float*          Lpart = (float*)(ws);                      //   393,216 B, reuses dead Xb

    prep_kernel<<<4648, 256, 0, stream>>>(X, (const float4*)adj, Wq, Wk, Wv, Wout,
                                          Xb, WT, WoutT, AsumT);
    proj_kernel<<<dim3(NN / 64, BB * HH, 3), 256, 0, stream>>>(Xb, WT, bq, bk, bv, Q, Kp, Vt);
    attn_kernel<<<768, 256, 0, stream>>>(Q, Kp, Vt, AsumT, Opart, Lpart);
    out_kernel<<<dim3((BB * NN) / 32, OUTD / 64), 256, 0, stream>>>(Opart, Lpart, WoutT, bout, out);
}